// Round 9
// baseline (161.413 us; speedup 1.0000x reference)
//
#include <hip/hip_runtime.h>
#include <hip/hip_cooperative_groups.h>

namespace cg = cooperative_groups;

#define VCNT 262144           // 64^3
#define NB 2
#define NT 128
#define HWPIX 65536           // 1*256*256
#define LN2  0.69314718055994531f
#define LN2X2 1.38629436111989062f

typedef float f32x2 __attribute__((ext_vector_type(2)));

static __device__ __forceinline__ float fast_exp2(float x) {
#if __has_builtin(__builtin_amdgcn_exp2f)
    return __builtin_amdgcn_exp2f(x);
#else
    float r; asm("v_exp_f32 %0, %1" : "=v"(r) : "v"(x)); return r;
#endif
}
static __device__ __forceinline__ float fast_rsq(float x) {
#if __has_builtin(__builtin_amdgcn_rsqf)
    return __builtin_amdgcn_rsqf(x);
#else
    float r; asm("v_rsq_f32 %0, %1" : "=v"(r) : "v"(x)); return r;
#endif
}

// ===========================================================================
// FUSED kernel (cooperative): Phase A = slice partial means, grid sync,
// Phase B = R6 recon body (lane-pair u-split, 4 vox/lane-pair).
// Grid: 1024 blocks x 256 threads (4 blocks/CU -> co-residency feasible).
// partials layout: 4 chunks/slice, partials[4*s + j].
// ===========================================================================
__global__ __launch_bounds__(256) void fused_kernel(
    const float* __restrict__ slices,
    const float* __restrict__ transforms,
    const int*   __restrict__ sidx,
    float*       __restrict__ partials,
    float*       __restrict__ out)
{
    const int tid  = threadIdx.x;
    const int lane = tid & 63;
    const int wid  = tid >> 6;

    // ---------------- Phase A: partial sums of needed slices --------------
    {
        const int g   = blockIdx.x;        // 0..1023
        const int s   = g >> 2;            // slice 0..255
        const int bb  = s >> 7;
        const int tsl = s & 127;

        __shared__ int neededA;
        if (tid == 0) neededA = 0;
        __syncthreads();
        if (tid < NT && sidx[(bb << 7) + tid] == tsl) neededA = 1;
        __syncthreads();

        if (neededA) {                     // uniform across block
            const int j = g & 3;           // quarter-slice chunk (64 KB)
            const float4* p = (const float4*)(slices + (size_t)s * HWPIX)
                            + j * 4096;
            float acc = 0.0f;
#pragma unroll
            for (int i = 0; i < 16; ++i) {
                float4 v = p[i * 256 + tid];
                acc += (v.x + v.y) + (v.z + v.w);
            }
#pragma unroll
            for (int off = 32; off > 0; off >>= 1)
                acc += __shfl_down(acc, off, 64);

            __shared__ float wsA[4];
            if (lane == 0) wsA[wid] = acc;
            __syncthreads();
            if (tid == 0)
                partials[g] = (wsA[0] + wsA[1]) + (wsA[2] + wsA[3]);
        }
    }

    cg::this_grid().sync();   // device-wide: partials now visible everywhere

    // ---------------- Phase B: recon (R6 body) ----------------------------
    __shared__ float4 ct[NT];   // LN2*x, LN2*y, LN2*z, k*mean
    __shared__ float  kk[NT];   // k (multiplicity)
    __shared__ int    cnt[NT];
    __shared__ int    wcnt[2];
    __shared__ int    ncnt;

    const int b = blockIdx.x >> 9;                         // 512 blocks/batch

    if (tid < NT) cnt[tid] = 0;
    __syncthreads();
    if (tid < NT) atomicAdd(&cnt[sidx[(b << 7) + tid]], 1);
    __syncthreads();

    const int  k       = (tid < NT) ? cnt[tid] : 0;
    const bool neededf = (k > 0);
    const unsigned long long mask = __ballot(neededf);
    if (tid < NT && lane == 0) wcnt[wid] = (int)__popcll(mask);
    __syncthreads();
    if (neededf) {
        const int pos = (int)__popcll(mask & ((1ull << lane) - 1ull))
                      + (wid ? wcnt[0] : 0);
        const float* tr = transforms + (size_t)((b << 7) + tid) * 6;
        const float4 q = *(const float4*)(partials + (size_t)((b << 7) + tid) * 4);
        float m = ((q.x + q.y) + (q.z + q.w)) * (1.0f / (float)HWPIX);
        const float fk = (float)k;
        ct[pos] = make_float4(tr[0] * LN2, tr[1] * LN2, tr[2] * LN2, fk * m);
        kk[pos] = fk;
    }
    if (tid == 0) ncnt = wcnt[0] + wcnt[1];
    __syncthreads();
    const int n = ncnt;

    const int g    = (lane >> 5) & 1;                 // u-table half
    const int quad = (wid << 5) + (lane & 31);        // 0..127 within block
    const int v0   = ((blockIdx.x & 511) << 9) + (quad << 2);

    const float fx  = (float)(v0 >> 12) * LN2;
    const float fy  = (float)((v0 >> 6) & 63) * LN2;
    const float fz0 = (float)(v0 & 63) * LN2;
    const f32x2 fzp = {fz0, fz0 + LN2};               // even/odd z pair

    f32x2 wsumA = {0.0f, 0.0f}, accA = {0.0f, 0.0f};  // z, z+1
    f32x2 wsumB = {0.0f, 0.0f}, accB = {0.0f, 0.0f};  // z+2, z+3

#pragma unroll 2
    for (int t = g; t < n; t += 2) {
        const float4 c  = ct[t];          // uniform per half-wave -> broadcast
        const float  kf = kk[t];
        const float dx = fx - c.x;
        const float dy = fy - c.y;
        const float base = fmaf(dy, dy, dx * dx);
        f32x2 dz0 = fzp - c.z;            // pair (z, z+1)
        f32x2 d2a = dz0 * dz0 + base;
        f32x2 dz1 = dz0 + LN2X2;          // pair (z+2, z+3)
        f32x2 d2b = dz1 * dz1 + base;

        f32x2 wA, wB;
        wA.x = fast_exp2(fast_rsq(d2a.x));   // e^(1/dist), coords ln2-scaled
        wA.y = fast_exp2(fast_rsq(d2a.y));
        wB.x = fast_exp2(fast_rsq(d2b.x));
        wB.y = fast_exp2(fast_rsq(d2b.y));

        wsumA += wA * kf;
        accA  += wA * c.w;
        wsumB += wB * kf;
        accB  += wB * c.w;
    }

    // combine the two u-halves (partner lane l^32)
    wsumA.x += __shfl_xor(wsumA.x, 32, 64);
    wsumA.y += __shfl_xor(wsumA.y, 32, 64);
    wsumB.x += __shfl_xor(wsumB.x, 32, 64);
    wsumB.y += __shfl_xor(wsumB.y, 32, 64);
    accA.x  += __shfl_xor(accA.x, 32, 64);
    accA.y  += __shfl_xor(accA.y, 32, 64);
    accB.x  += __shfl_xor(accB.x, 32, 64);
    accB.y  += __shfl_xor(accB.y, 32, 64);

    if ((lane >> 5) == 0) {               // one writer per voxel quad
        float4 o;
        o.x = accA.x / wsumA.x;
        o.y = accA.y / wsumA.y;
        o.z = accB.x / wsumB.x;
        o.w = accB.y / wsumB.y;
        *(float4*)(out + (size_t)b * VCNT + v0) = o;
    }
}

// ===========================================================================
// Fallback path (two plain kernels) — exact R6 code, used only if the
// cooperative launch is rejected. partials layout: 8 chunks/slice.
// ===========================================================================
__global__ __launch_bounds__(256) void slice_partial_kernel(
    const float* __restrict__ slices, const int* __restrict__ sidx,
    float* __restrict__ partials)
{
    const int s   = blockIdx.x >> 3;
    const int b   = s >> 7;
    const int tsl = s & 127;

    __shared__ int needed;
    if (threadIdx.x == 0) needed = 0;
    __syncthreads();
    if (threadIdx.x < NT && sidx[(b << 7) + threadIdx.x] == tsl) needed = 1;
    __syncthreads();
    if (!needed) return;

    const int j = blockIdx.x & 7;
    const float4* p = (const float4*)(slices + (size_t)s * HWPIX) + j * 2048;

    float acc = 0.0f;
#pragma unroll
    for (int i = 0; i < 8; ++i) {
        float4 v = p[i * 256 + threadIdx.x];
        acc += (v.x + v.y) + (v.z + v.w);
    }
#pragma unroll
    for (int off = 32; off > 0; off >>= 1)
        acc += __shfl_down(acc, off, 64);

    __shared__ float ws[4];
    const int lane = threadIdx.x & 63;
    const int wid  = threadIdx.x >> 6;
    if (lane == 0) ws[wid] = acc;
    __syncthreads();
    if (threadIdx.x == 0)
        partials[blockIdx.x] = (ws[0] + ws[1]) + (ws[2] + ws[3]);
}

__global__ __launch_bounds__(256) void recon_kernel(
    const float* __restrict__ transforms,
    const int*   __restrict__ sidx,
    const float* __restrict__ partials,
    float*       __restrict__ out)
{
    __shared__ float4 ct[NT];
    __shared__ float  kk[NT];
    __shared__ int    cnt[NT];
    __shared__ int    wcnt[2];
    __shared__ int    ncnt;

    const int tid  = threadIdx.x;
    const int lane = tid & 63;
    const int wid  = tid >> 6;
    const int b    = blockIdx.x >> 9;

    if (tid < NT) cnt[tid] = 0;
    __syncthreads();
    if (tid < NT) atomicAdd(&cnt[sidx[(b << 7) + tid]], 1);
    __syncthreads();

    const int  k       = (tid < NT) ? cnt[tid] : 0;
    const bool neededf = (k > 0);
    const unsigned long long mask = __ballot(neededf);
    if (tid < NT && lane == 0) wcnt[wid] = (int)__popcll(mask);
    __syncthreads();
    if (neededf) {
        const int pos = (int)__popcll(mask & ((1ull << lane) - 1ull))
                      + (wid ? wcnt[0] : 0);
        const float* tr = transforms + (size_t)((b << 7) + tid) * 6;
        const float* pp = partials   + (size_t)((b << 7) + tid) * 8;
        float m = 0.0f;
#pragma unroll
        for (int i = 0; i < 8; ++i) m += pp[i];
        m *= (1.0f / (float)HWPIX);
        const float fk = (float)k;
        ct[pos] = make_float4(tr[0] * LN2, tr[1] * LN2, tr[2] * LN2, fk * m);
        kk[pos] = fk;
    }
    if (tid == 0) ncnt = wcnt[0] + wcnt[1];
    __syncthreads();
    const int n = ncnt;

    const int g    = (lane >> 5) & 1;
    const int quad = (wid << 5) + (lane & 31);
    const int v0   = ((blockIdx.x & 511) << 9) + (quad << 2);

    const float fx  = (float)(v0 >> 12) * LN2;
    const float fy  = (float)((v0 >> 6) & 63) * LN2;
    const float fz0 = (float)(v0 & 63) * LN2;
    const f32x2 fzp = {fz0, fz0 + LN2};

    f32x2 wsumA = {0.0f, 0.0f}, accA = {0.0f, 0.0f};
    f32x2 wsumB = {0.0f, 0.0f}, accB = {0.0f, 0.0f};

#pragma unroll 2
    for (int t = g; t < n; t += 2) {
        const float4 c  = ct[t];
        const float  kf = kk[t];
        const float dx = fx - c.x;
        const float dy = fy - c.y;
        const float base = fmaf(dy, dy, dx * dx);
        f32x2 dz0 = fzp - c.z;
        f32x2 d2a = dz0 * dz0 + base;
        f32x2 dz1 = dz0 + LN2X2;
        f32x2 d2b = dz1 * dz1 + base;

        f32x2 wA, wB;
        wA.x = fast_exp2(fast_rsq(d2a.x));
        wA.y = fast_exp2(fast_rsq(d2a.y));
        wB.x = fast_exp2(fast_rsq(d2b.x));
        wB.y = fast_exp2(fast_rsq(d2b.y));

        wsumA += wA * kf;
        accA  += wA * c.w;
        wsumB += wB * kf;
        accB  += wB * c.w;
    }

    wsumA.x += __shfl_xor(wsumA.x, 32, 64);
    wsumA.y += __shfl_xor(wsumA.y, 32, 64);
    wsumB.x += __shfl_xor(wsumB.x, 32, 64);
    wsumB.y += __shfl_xor(wsumB.y, 32, 64);
    accA.x  += __shfl_xor(accA.x, 32, 64);
    accA.y  += __shfl_xor(accA.y, 32, 64);
    accB.x  += __shfl_xor(accB.x, 32, 64);
    accB.y  += __shfl_xor(accB.y, 32, 64);

    if ((lane >> 5) == 0) {
        float4 o;
        o.x = accA.x / wsumA.x;
        o.y = accA.y / wsumA.y;
        o.z = accB.x / wsumB.x;
        o.w = accB.y / wsumB.y;
        *(float4*)(out + (size_t)b * VCNT + v0) = o;
    }
}

// ---------------------------------------------------------------------------
extern "C" void kernel_launch(void* const* d_in, const int* in_sizes, int n_in,
                              void* d_out, int out_size, void* d_ws, size_t ws_size,
                              hipStream_t stream)
{
    const float* slices     = (const float*)d_in[0];  // (2,128,1,256,256) f32
    const float* transforms = (const float*)d_in[1];  // (2,128,6) f32
    const int*   sidx       = (const int*)d_in[2];    // (2,128) i32
    float* out      = (float*)d_out;                  // (2,1,64,64,64) f32
    float* partials = (float*)d_ws;                   // scratch

    void* args[5] = { (void*)&slices, (void*)&transforms, (void*)&sidx,
                      (void*)&partials, (void*)&out };
    hipError_t e = hipLaunchCooperativeKernel((const void*)fused_kernel,
                                              dim3(1024), dim3(256),
                                              args, 0, stream);
    if (e != hipSuccess) {
        // fallback: proven two-kernel R6 path
        slice_partial_kernel<<<NB * NT * 8, 256, 0, stream>>>(slices, sidx, partials);
        recon_kernel<<<NB * VCNT / 512, 256, 0, stream>>>(transforms, sidx, partials, out);
    }
}

// Round 10
// 25.540 us; speedup vs baseline: 6.3199x; 6.3199x over previous
//
#include <hip/hip_runtime.h>

#define VCNT 262144           // 64^3
#define NB 2
#define NT 128
#define HWPIX 65536           // 1*256*256
#define LN2   0.69314718055994531f
#define LN2X2 1.38629436111989062f
#define LN2X4 2.77258872223978124f
#define LN2X6 4.15888308335967186f

typedef float f32x2 __attribute__((ext_vector_type(2)));

static __device__ __forceinline__ float fast_exp2(float x) {
#if __has_builtin(__builtin_amdgcn_exp2f)
    return __builtin_amdgcn_exp2f(x);
#else
    float r; asm("v_exp_f32 %0, %1" : "=v"(r) : "v"(x)); return r;
#endif
}
static __device__ __forceinline__ float fast_rsq(float x) {
#if __has_builtin(__builtin_amdgcn_rsqf)
    return __builtin_amdgcn_rsqf(x);
#else
    float r; asm("v_rsq_f32 %0, %1" : "=v"(r) : "v"(x)); return r;
#endif
}

// ---------------------------------------------------------------------------
// Kernel 1: partial slice sums, needed slices only. 8 blocks/slice = 2048.
// (R6 version, verbatim — known-good.)
// ---------------------------------------------------------------------------
__global__ __launch_bounds__(256) void slice_partial_kernel(
    const float* __restrict__ slices, const int* __restrict__ sidx,
    float* __restrict__ partials)
{
    const int s   = blockIdx.x >> 3;   // 0..255
    const int b   = s >> 7;
    const int tsl = s & 127;

    __shared__ int needed;
    if (threadIdx.x == 0) needed = 0;
    __syncthreads();
    if (threadIdx.x < NT && sidx[(b << 7) + threadIdx.x] == tsl) needed = 1;
    __syncthreads();
    if (!needed) return;               // uniform across block

    const int j = blockIdx.x & 7;
    const float4* p = (const float4*)(slices + (size_t)s * HWPIX) + j * 2048;

    float acc = 0.0f;
#pragma unroll
    for (int i = 0; i < 8; ++i) {
        float4 v = p[i * 256 + threadIdx.x];
        acc += (v.x + v.y) + (v.z + v.w);
    }
#pragma unroll
    for (int off = 32; off > 0; off >>= 1)
        acc += __shfl_down(acc, off, 64);

    __shared__ float ws[4];
    const int lane = threadIdx.x & 63;
    const int wid  = threadIdx.x >> 6;
    if (lane == 0) ws[wid] = acc;
    __syncthreads();
    if (threadIdx.x == 0)
        partials[blockIdx.x] = (ws[0] + ws[1]) + (ws[2] + ws[3]);
}

// ---------------------------------------------------------------------------
// Kernel 2: voxel reconstruction.
//  - O(1) LDS-atomic dedup (n unique u of 128, multiplicity k)
//  - 8 z-consecutive voxels per COLUMN; each column owned by 4 lanes
//    (l, l+16, l+32, l+48) that process interleaved quarters of the u-table
//    (t = g, g+4, ...). dx^2+dy^2 and LDS reads amortized over 8 voxels;
//    dz chains via pk adds. Combine via __shfl_xor(16) + __shfl_xor(32).
//  - coords pre-scaled by ln2 so w = exp(1/dist) = exp2(rsq(d2)).
// Grid: NB*VCNT/512 = 1024 blocks x 256 threads (4 waves/SIMD).
// Per wave, the 4 lane-groups read ct[t..t+3]: consecutive float4s ->
// distinct banks, conflict-free broadcast.
// ---------------------------------------------------------------------------
__global__ __launch_bounds__(256) void recon_kernel(
    const float* __restrict__ transforms,
    const int*   __restrict__ sidx,
    const float* __restrict__ partials,
    float*       __restrict__ out)
{
    __shared__ float4 ct[NT];   // LN2*x, LN2*y, LN2*z, k*mean
    __shared__ float  kk[NT];   // k (multiplicity)
    __shared__ int    cnt[NT];
    __shared__ int    wcnt[2];
    __shared__ int    ncnt;

    const int tid  = threadIdx.x;
    const int lane = tid & 63;
    const int wid  = tid >> 6;
    const int b    = blockIdx.x >> 9;                      // 512 blocks/batch

    // ---- dedup prologue (threads 0..127), O(1) via LDS atomics ----
    if (tid < NT) cnt[tid] = 0;
    __syncthreads();
    if (tid < NT) atomicAdd(&cnt[sidx[(b << 7) + tid]], 1);
    __syncthreads();

    const int  k       = (tid < NT) ? cnt[tid] : 0;
    const bool neededf = (k > 0);
    const unsigned long long mask = __ballot(neededf);
    if (tid < NT && lane == 0) wcnt[wid] = (int)__popcll(mask);
    __syncthreads();
    if (neededf) {
        const int pos = (int)__popcll(mask & ((1ull << lane) - 1ull))
                      + (wid ? wcnt[0] : 0);
        const float* tr = transforms + (size_t)((b << 7) + tid) * 6;
        const float* pp = partials   + (size_t)((b << 7) + tid) * 8;
        float m = 0.0f;
#pragma unroll
        for (int i = 0; i < 8; ++i) m += pp[i];
        m *= (1.0f / (float)HWPIX);
        const float fk = (float)k;
        ct[pos] = make_float4(tr[0] * LN2, tr[1] * LN2, tr[2] * LN2, fk * m);
        kk[pos] = fk;
    }
    if (tid == 0) ncnt = wcnt[0] + wcnt[1];
    __syncthreads();
    const int n = ncnt;

    // ---- column assignment: 64 columns/block, 4 lanes per column ----
    const int g   = (lane >> 4) & 3;               // u-table quarter
    const int col = (wid << 4) + (lane & 15);      // 0..63
    const int v0  = ((blockIdx.x & 511) << 9) + (col << 3);  // 8 voxels

    const float fx  = (float)(v0 >> 12) * LN2;
    const float fy  = (float)((v0 >> 6) & 63) * LN2;
    const float fz0 = (float)(v0 & 63) * LN2;
    const f32x2 fzp = {fz0, fz0 + LN2};            // (z, z+1)

    f32x2 ws0 = {0,0}, ws1 = {0,0}, ws2 = {0,0}, ws3 = {0,0};
    f32x2 ac0 = {0,0}, ac1 = {0,0}, ac2 = {0,0}, ac3 = {0,0};

#pragma unroll 2
    for (int t = g; t < n; t += 4) {
        const float4 c  = ct[t];        // 4 consecutive entries/wave: no conflict
        const float  kf = kk[t];
        const float dx = fx - c.x;
        const float dy = fy - c.y;
        const float base = fmaf(dy, dy, dx * dx);

        f32x2 d0 = fzp - c.z;           // (z, z+1)
        f32x2 d1 = d0 + LN2X2;          // (z+2, z+3)
        f32x2 d2 = d0 + LN2X4;          // (z+4, z+5)
        f32x2 d3 = d0 + LN2X6;          // (z+6, z+7)
        f32x2 q0 = d0 * d0 + base;      // pk_fma
        f32x2 q1 = d1 * d1 + base;
        f32x2 q2 = d2 * d2 + base;
        f32x2 q3 = d3 * d3 + base;

        f32x2 w0, w1, w2, w3;
        w0.x = fast_exp2(fast_rsq(q0.x));  w0.y = fast_exp2(fast_rsq(q0.y));
        w1.x = fast_exp2(fast_rsq(q1.x));  w1.y = fast_exp2(fast_rsq(q1.y));
        w2.x = fast_exp2(fast_rsq(q2.x));  w2.y = fast_exp2(fast_rsq(q2.y));
        w3.x = fast_exp2(fast_rsq(q3.x));  w3.y = fast_exp2(fast_rsq(q3.y));

        ws0 += w0 * kf;   ac0 += w0 * c.w;
        ws1 += w1 * kf;   ac1 += w1 * c.w;
        ws2 += w2 * kf;   ac2 += w2 * c.w;
        ws3 += w3 * kf;   ac3 += w3 * c.w;
    }

    // ---- combine the 4 u-quarters (lanes l, l+16, l+32, l+48) ----
#define CMB(r) r.x += __shfl_xor(r.x, 16, 64); r.y += __shfl_xor(r.y, 16, 64); \
               r.x += __shfl_xor(r.x, 32, 64); r.y += __shfl_xor(r.y, 32, 64);
    CMB(ws0) CMB(ws1) CMB(ws2) CMB(ws3)
    CMB(ac0) CMB(ac1) CMB(ac2) CMB(ac3)
#undef CMB

    if ((lane & 48) == 0) {            // one writer per column
        float4 oa, ob;
        oa.x = ac0.x / ws0.x;  oa.y = ac0.y / ws0.y;
        oa.z = ac1.x / ws1.x;  oa.w = ac1.y / ws1.y;
        ob.x = ac2.x / ws2.x;  ob.y = ac2.y / ws2.y;
        ob.z = ac3.x / ws3.x;  ob.w = ac3.y / ws3.y;
        float* o = out + (size_t)b * VCNT + v0;
        *(float4*)o       = oa;
        *(float4*)(o + 4) = ob;
    }
}

// ---------------------------------------------------------------------------
extern "C" void kernel_launch(void* const* d_in, const int* in_sizes, int n_in,
                              void* d_out, int out_size, void* d_ws, size_t ws_size,
                              hipStream_t stream)
{
    const float* slices     = (const float*)d_in[0];  // (2,128,1,256,256) f32
    const float* transforms = (const float*)d_in[1];  // (2,128,6) f32
    const int*   sidx       = (const int*)d_in[2];    // (2,128) i32
    float* out      = (float*)d_out;                  // (2,1,64,64,64) f32
    float* partials = (float*)d_ws;                   // 2048 floats scratch

    slice_partial_kernel<<<NB * NT * 8, 256, 0, stream>>>(slices, sidx, partials);
    recon_kernel<<<NB * VCNT / 512, 256, 0, stream>>>(transforms, sidx, partials, out);
}